// Round 1
// baseline (946.012 us; speedup 1.0000x reference)
//
#include <hip/hip_runtime.h>
#include <math.h>

// ---------------------------------------------------------------------------
// GraphProjection: project N=65536 points into V=3 camera views, gather
// multi-scale CNN features (batch index faithfully truncates to 0), reduce
// max/mean/biased-std over views. Output [N, 3 + 3*960] f32.
//
// Structure (this revision): the timed graph is harness-poison-fill (~485us,
// fixed) + our kernels. Previous k_main mixed a 3-thread double-precision
// geometry phase (VGPR-inflating, barrier-serialized) with the f32 streaming
// phase. Now split:
//   k_setup     : camera math -> 48 doubles in ws            (1 thread)
//   k_transpose : feat [C,H,W] -> tbl [H*W,C], batch 0 only  (~10us)
//   k_geom      : per-point f64 projection -> 12 table offsets + xyz copy
//   k_gather    : one WAVE per point, pure f32 gather+stats, nontemporal
//                 stores (keeps the 1.5MB table L2-resident), no LDS/barrier
// ---------------------------------------------------------------------------

#define TBL_TOTAL 376320            // 56*56*64 + 28*28*128 + 14*14*256 + 7*7*512
#define TBL_OFF0  0
#define TBL_OFF1  200704
#define TBL_OFF2  301056
#define TBL_OFF3  351232

__device__ __forceinline__ void compute_cams(const float* __restrict__ cams,
                                             double M[3][3], double o0[3],
                                             double cm[3][3][3], double om[3][3]) {
  // PI is np.float32(np.pi) in the reference; PI/180 stays f32-rounded.
  const double DEG  = (double)(3.14159274101257324f / 180.0f);
  const double PI_D = (double)3.14159274101257324f;
  for (int v = 0; v < 3; ++v) {
    double th = (double)cams[v * 5 + 0] * DEG;
    double ph = (double)cams[v * 5 + 1] * DEG;
    double dd = (double)cams[v * 5 + 3];
    double camy = dd * sin(ph);
    double lens = dd * cos(ph);
    double camx = lens * cos(th);
    double camz = lens * sin(th);
    double Zx = camx, Zy = camy, Zz = camz;
    double Yx = camy * cos(th + PI_D), Yy = lens, Yz = camy * sin(th + PI_D);
    double Xx = Yy * Zz - Yz * Zy;
    double Xy = Yz * Zx - Yx * Zz;
    double Xz = Yx * Zy - Yy * Zx;
    double nX = sqrt(Xx * Xx + Xy * Xy + Xz * Xz);
    double nY = sqrt(Yx * Yx + Yy * Yy + Yz * Yz);
    double nZ = sqrt(Zx * Zx + Zy * Zy + Zz * Zz);
    cm[v][0][0] = Xx / nX; cm[v][0][1] = Xy / nX; cm[v][0][2] = Xz / nX;
    cm[v][1][0] = Yx / nY; cm[v][1][1] = Yy / nY; cm[v][1][2] = Yz / nY;
    cm[v][2][0] = Zx / nZ; cm[v][2][1] = Zy / nZ; cm[v][2][2] = Zz / nZ;
    om[v][0] = Zx; om[v][1] = Zy; om[v][2] = Zz;
  }
  // A = c0^T ; M = inv(A) via adjugate (double precision).
  double a00 = cm[0][0][0], a01 = cm[0][1][0], a02 = cm[0][2][0];
  double a10 = cm[0][0][1], a11 = cm[0][1][1], a12 = cm[0][2][1];
  double a20 = cm[0][0][2], a21 = cm[0][1][2], a22 = cm[0][2][2];
  double det = a00 * (a11 * a22 - a12 * a21)
             - a01 * (a10 * a22 - a12 * a20)
             + a02 * (a10 * a21 - a11 * a20);
  M[0][0] = (a11 * a22 - a12 * a21) / det;
  M[0][1] = (a02 * a21 - a01 * a22) / det;
  M[0][2] = (a01 * a12 - a02 * a11) / det;
  M[1][0] = (a12 * a20 - a10 * a22) / det;
  M[1][1] = (a00 * a22 - a02 * a20) / det;
  M[1][2] = (a02 * a10 - a00 * a12) / det;
  M[2][0] = (a10 * a21 - a11 * a20) / det;
  M[2][1] = (a01 * a20 - a00 * a21) / det;
  M[2][2] = (a00 * a11 - a01 * a10) / det;
  o0[0] = om[0][0]; o0[1] = om[0][1]; o0[2] = om[0][2];
}

// Tiny setup kernel: camera params -> 48 doubles in workspace.
// Layout: M[9] | o0[3] | c[3][3][3] (27) | o[3][3] (9)
__global__ void k_setup(const float* __restrict__ cams, double* __restrict__ P) {
  if (threadIdx.x != 0 || blockIdx.x != 0) return;
  double M[3][3], o0[3], cm[3][3][3], om[3][3];
  compute_cams(cams, M, o0, cm, om);
  int i = 0;
  for (int r = 0; r < 3; ++r)
    for (int k = 0; k < 3; ++k) P[i++] = M[r][k];
  for (int k = 0; k < 3; ++k) P[i++] = o0[k];
  for (int v = 0; v < 3; ++v)
    for (int r = 0; r < 3; ++r)
      for (int k = 0; k < 3; ++k) P[i++] = cm[v][r][k];
  for (int v = 0; v < 3; ++v)
    for (int k = 0; k < 3; ++k) P[i++] = om[v][k];
}

// Transpose batch 0 of each feature level from [C,H,W] -> [H*W, C].
__global__ void k_transpose(const float* __restrict__ f0, const float* __restrict__ f1,
                            const float* __restrict__ f2, const float* __restrict__ f3,
                            float* __restrict__ tbl) {
  int i = blockIdx.x * 256 + threadIdx.x;
  if (i >= TBL_TOTAL) return;
  const float* src;
  int j, cmask, clog, HW;
  if (i < TBL_OFF1)      { src = f0; j = i;            cmask = 63;  clog = 6; HW = 3136; }
  else if (i < TBL_OFF2) { src = f1; j = i - TBL_OFF1; cmask = 127; clog = 7; HW = 784;  }
  else if (i < TBL_OFF3) { src = f2; j = i - TBL_OFF2; cmask = 255; clog = 8; HW = 196;  }
  else                   { src = f3; j = i - TBL_OFF3; cmask = 511; clog = 9; HW = 49;   }
  int c  = j & cmask;
  int hw = j >> clog;
  tbl[i] = src[c * HW + hw];   // batch 0 only (faithful truncated batch index)
}

// Per-point geometry: all double-precision work lives here (dense, all lanes
// active). Emits 12 absolute tbl offsets per point + copies xyz passthrough.
__global__ __launch_bounds__(256) void k_geom(const float* __restrict__ inpts,
                                              const double* __restrict__ P,
                                              int* __restrict__ off,
                                              float* __restrict__ out, int N) {
  int p = blockIdx.x * 256 + threadIdx.x;
  if (p >= N) return;
  double x = (double)inpts[p * 3 + 0];
  double y = (double)inpts[p * 3 + 1];
  double z = (double)inpts[p * 3 + 2];
  // point_origin = inputs @ inv(c0^T) + o0
  double p0 = x * P[0] + y * P[3] + z * P[6] + P[9];
  double p1 = x * P[1] + y * P[4] + z * P[7] + P[10];
  double p2 = x * P[2] + y * P[5] + z * P[8] + P[11];
  int4 r[3];
  #pragma unroll
  for (int v = 0; v < 3; ++v) {
    const double* cmv = P + 12 + v * 9;
    const double* ovv = P + 39 + v * 3;
    double q0 = p0 - ovv[0], q1 = p1 - ovv[1], q2 = p2 - ovv[2];
    double Xc = q0 * cmv[0] + q1 * cmv[1] + q2 * cmv[2];
    double Yc = q0 * cmv[3] + q1 * cmv[4] + q2 * cmv[5];
    double Zc = q0 * cmv[6] + q1 * cmv[7] + q2 * cmv[8];
    double nz = -Zc;
    double hv = 248.0 * (-Yc) / nz + 112.0;
    double wv = 248.0 * Xc / nz + 112.0;
    if (isnan(hv)) hv = 0.0;
    if (isnan(wv)) wv = 0.0;
    hv = fmin(fmax(hv, 0.0), 223.0);
    wv = fmin(fmax(wv, 0.0), 223.0);
    // scales 224/size = {4,8,16,32} are exact powers of two
    int h0 = (int)(hv * 0.25),    w0 = (int)(wv * 0.25);
    int h1 = (int)(hv * 0.125),   w1 = (int)(wv * 0.125);
    int h2 = (int)(hv * 0.0625),  w2 = (int)(wv * 0.0625);
    int h3 = (int)(hv * 0.03125), w3 = (int)(wv * 0.03125);
    r[v].x = TBL_OFF0 + (h0 * 56 + w0) * 64;
    r[v].y = TBL_OFF1 + (h1 * 28 + w1) * 128;
    r[v].z = TBL_OFF2 + (h2 * 14 + w2) * 256;
    r[v].w = TBL_OFF3 + (h3 * 7  + w3) * 512;
  }
  int4* op = (int4*)(off + p * 12);   // p*48 bytes, 16B-aligned
  op[0] = r[0]; op[1] = r[1]; op[2] = r[2];
  out[p * 2883 + 0] = inpts[p * 3 + 0];
  out[p * 2883 + 1] = inpts[p * 3 + 1];
  out[p * 2883 + 2] = inpts[p * 3 + 2];
}

// One wave per point: 15 fully-unrolled 64-channel slabs, level known at
// compile time per slab (no divergence, no LDS, no barrier, no doubles).
// Nontemporal stores keep the write stream from evicting tbl out of L2.
__global__ __launch_bounds__(256) void k_gather(const int* __restrict__ off,
                                                const float* __restrict__ tbl,
                                                float* __restrict__ out, int N) {
  const int wid = (blockIdx.x << 2) | (threadIdx.x >> 6);   // 4 waves/block
  if (wid >= N) return;
  const int lane = threadIdx.x & 63;
  const int4* ob = (const int4*)(off + wid * 12);
  const int4 o0 = ob[0];   // view 0: offsets for levels 0..3
  const int4 o1 = ob[1];   // view 1
  const int4 o2 = ob[2];   // view 2
  float* __restrict__ row = out + (size_t)wid * 2883;

#define DO64(BASE_C, OO0, OO1, OO2, CL)                         \
  {                                                             \
    float v0 = tbl[(OO0) + (CL)];                               \
    float v1 = tbl[(OO1) + (CL)];                               \
    float v2 = tbl[(OO2) + (CL)];                               \
    float mx = fmaxf(fmaxf(v0, v1), v2);                        \
    float sm = (v0 + v1) + v2;                                  \
    float mean = sm / 3.0f;                                     \
    float d0 = v0 - mean, d1 = v1 - mean, d2 = v2 - mean;       \
    float var = ((d0 * d0 + d1 * d1) + d2 * d2) / 3.0f;         \
    float sd = sqrtf(var);                                      \
    int c = (BASE_C) + (CL);                                    \
    __builtin_nontemporal_store(mx,   row + 3 + c);             \
    __builtin_nontemporal_store(mean, row + 963 + c);           \
    __builtin_nontemporal_store(sd,   row + 1923 + c);          \
  }

  // level 0: channels [0,64)
  DO64(0, o0.x, o1.x, o2.x, lane);
  // level 1: channels [64,192)
  #pragma unroll
  for (int j = 0; j < 2; ++j) DO64(64, o0.y, o1.y, o2.y, lane + 64 * j);
  // level 2: channels [192,448)
  #pragma unroll
  for (int j = 0; j < 4; ++j) DO64(192, o0.z, o1.z, o2.z, lane + 64 * j);
  // level 3: channels [448,960)
  #pragma unroll
  for (int j = 0; j < 8; ++j) DO64(448, o0.w, o1.w, o2.w, lane + 64 * j);
#undef DO64
}

// ---------------------------------------------------------------------------
// Fallback (ws too small): previous-session fused kernel, unchanged.
// ---------------------------------------------------------------------------
template <bool TRANSPOSED>
__global__ __launch_bounds__(256) void k_main(
    const float* __restrict__ inpts, const float* __restrict__ cams,
    const double* __restrict__ P, const float* __restrict__ tbl,
    const float* __restrict__ f0, const float* __restrict__ f1,
    const float* __restrict__ f2, const float* __restrict__ f3,
    float* __restrict__ out) {
  __shared__ int s_off[3][4];
  const int p = blockIdx.x;
  const int tid = threadIdx.x;

  if (tid < 3) {
    const int v = tid;
    double M[3][3], o0[3], cmv[3][3], ovv[3];
    if (TRANSPOSED) {
      M[0][0] = P[0]; M[0][1] = P[1]; M[0][2] = P[2];
      M[1][0] = P[3]; M[1][1] = P[4]; M[1][2] = P[5];
      M[2][0] = P[6]; M[2][1] = P[7]; M[2][2] = P[8];
      o0[0] = P[9]; o0[1] = P[10]; o0[2] = P[11];
      for (int r = 0; r < 3; ++r)
        for (int k = 0; k < 3; ++k) cmv[r][k] = P[12 + v * 9 + r * 3 + k];
      ovv[0] = P[39 + v * 3 + 0]; ovv[1] = P[39 + v * 3 + 1]; ovv[2] = P[39 + v * 3 + 2];
    } else {
      double cm[3][3][3], om[3][3];
      compute_cams(cams, M, o0, cm, om);
      for (int r = 0; r < 3; ++r)
        for (int k = 0; k < 3; ++k) cmv[r][k] = cm[v][r][k];
      ovv[0] = om[v][0]; ovv[1] = om[v][1]; ovv[2] = om[v][2];
    }
    double x = (double)inpts[p * 3 + 0];
    double y = (double)inpts[p * 3 + 1];
    double z = (double)inpts[p * 3 + 2];
    double p0 = x * M[0][0] + y * M[1][0] + z * M[2][0] + o0[0];
    double p1 = x * M[0][1] + y * M[1][1] + z * M[2][1] + o0[1];
    double p2 = x * M[0][2] + y * M[1][2] + z * M[2][2] + o0[2];
    double q0 = p0 - ovv[0], q1 = p1 - ovv[1], q2 = p2 - ovv[2];
    double Xc = q0 * cmv[0][0] + q1 * cmv[0][1] + q2 * cmv[0][2];
    double Yc = q0 * cmv[1][0] + q1 * cmv[1][1] + q2 * cmv[1][2];
    double Zc = q0 * cmv[2][0] + q1 * cmv[2][1] + q2 * cmv[2][2];
    double nz = -Zc;
    double hv = 248.0 * (-Yc) / nz + 112.0;
    double wv = 248.0 * Xc / nz + 112.0;
    if (isnan(hv)) hv = 0.0;
    if (isnan(wv)) wv = 0.0;
    hv = fmin(fmax(hv, 0.0), 223.0);
    wv = fmin(fmax(wv, 0.0), 223.0);
    int h0 = (int)(hv * 0.25),    w0 = (int)(wv * 0.25);
    int h1 = (int)(hv * 0.125),   w1 = (int)(wv * 0.125);
    int h2 = (int)(hv * 0.0625),  w2 = (int)(wv * 0.0625);
    int h3 = (int)(hv * 0.03125), w3 = (int)(wv * 0.03125);
    if (TRANSPOSED) {
      s_off[v][0] = TBL_OFF0 + (h0 * 56 + w0) * 64;
      s_off[v][1] = TBL_OFF1 + (h1 * 28 + w1) * 128;
      s_off[v][2] = TBL_OFF2 + (h2 * 14 + w2) * 256;
      s_off[v][3] = TBL_OFF3 + (h3 * 7  + w3) * 512;
    } else {
      s_off[v][0] = h0 * 56 + w0;
      s_off[v][1] = h1 * 28 + w1;
      s_off[v][2] = h2 * 14 + w2;
      s_off[v][3] = h3 * 7  + w3;
    }
    out[p * 2883 + v] = inpts[p * 3 + v];   // passthrough xyz
  }
  __syncthreads();

  const int row = p * 2883;
  for (int c = tid; c < 960; c += 256) {
    int l, cl;
    if (c < 64)       { l = 0; cl = c; }
    else if (c < 192) { l = 1; cl = c - 64; }
    else if (c < 448) { l = 2; cl = c - 192; }
    else              { l = 3; cl = c - 448; }
    float v0, v1, v2;
    if (TRANSPOSED) {
      v0 = tbl[s_off[0][l] + cl];
      v1 = tbl[s_off[1][l] + cl];
      v2 = tbl[s_off[2][l] + cl];
    } else {
      const float* f = (l == 0) ? f0 : (l == 1) ? f1 : (l == 2) ? f2 : f3;
      const int HW   = (l == 0) ? 3136 : (l == 1) ? 784 : (l == 2) ? 196 : 49;
      v0 = f[cl * HW + s_off[0][l]];
      v1 = f[cl * HW + s_off[1][l]];
      v2 = f[cl * HW + s_off[2][l]];
    }
    float mx = fmaxf(fmaxf(v0, v1), v2);
    float sm = (v0 + v1) + v2;
    float mean = sm / 3.0f;
    float d0 = v0 - mean, d1 = v1 - mean, d2 = v2 - mean;
    float var = ((d0 * d0 + d1 * d1) + d2 * d2) / 3.0f;
    float sd = sqrtf(var);
    out[row + 3 + c]    = mx;
    out[row + 963 + c]  = mean;
    out[row + 1923 + c] = sd;
  }
}

extern "C" void kernel_launch(void* const* d_in, const int* in_sizes, int n_in,
                              void* d_out, int out_size, void* d_ws, size_t ws_size,
                              hipStream_t stream) {
  const float* inpts = (const float*)d_in[0];
  const float* cams  = (const float*)d_in[1];
  const float* f0    = (const float*)d_in[2];
  const float* f1    = (const float*)d_in[3];
  const float* f2    = (const float*)d_in[4];
  const float* f3    = (const float*)d_in[5];
  float* out = (float*)d_out;
  const int N = in_sizes[0] / 3;

  const size_t TBL_BYTE_OFF = 512;
  const size_t OFF_BYTE_OFF = TBL_BYTE_OFF + (size_t)TBL_TOTAL * sizeof(float); // 1505792, 16B-aligned
  const size_t NEED_FULL = OFF_BYTE_OFF + (size_t)N * 12 * sizeof(int);
  const size_t NEED_MID  = TBL_BYTE_OFF + (size_t)TBL_TOTAL * sizeof(float);

  if (ws_size >= NEED_FULL) {
    double* P  = (double*)d_ws;
    float* tbl = (float*)((char*)d_ws + TBL_BYTE_OFF);
    int*   off = (int*)((char*)d_ws + OFF_BYTE_OFF);
    k_setup<<<1, 64, 0, stream>>>(cams, P);
    k_transpose<<<(TBL_TOTAL + 255) / 256, 256, 0, stream>>>(f0, f1, f2, f3, tbl);
    k_geom<<<(N + 255) / 256, 256, 0, stream>>>(inpts, P, off, out, N);
    k_gather<<<(N + 3) / 4, 256, 0, stream>>>(off, tbl, out, N);
  } else if (ws_size >= NEED_MID) {
    double* P  = (double*)d_ws;
    float* tbl = (float*)((char*)d_ws + TBL_BYTE_OFF);
    k_setup<<<1, 64, 0, stream>>>(cams, P);
    k_transpose<<<(TBL_TOTAL + 255) / 256, 256, 0, stream>>>(f0, f1, f2, f3, tbl);
    k_main<true><<<N, 256, 0, stream>>>(inpts, cams, P, tbl, f0, f1, f2, f3, out);
  } else {
    // Fallback: no workspace -> inline camera math, direct (uncoalesced) gather.
    k_main<false><<<N, 256, 0, stream>>>(inpts, cams, nullptr, nullptr, f0, f1, f2, f3, out);
  }
}

// Round 2
// 818.631 us; speedup vs baseline: 1.1556x; 1.1556x over previous
//
#include <hip/hip_runtime.h>
#include <math.h>

// ---------------------------------------------------------------------------
// GraphProjection: project N=65536 points into V=3 camera views, gather
// multi-scale CNN features (batch index faithfully truncates to 0), reduce
// max/mean/biased-std over views. Output [N, 3 + 3*960] f32.
//
// Pipeline:
//   k_setup     : camera math -> 48 doubles in ws            (1 thread)
//   k_transpose : feat [C,H,W] -> tbl [H*W,C], batch 0 only  (~10us)
//   k_geom      : per-point f64 projection -> 12 table offsets (dense)
//   k_gather    : one WAVE per point, pure f32 gather+stats. NORMAL stores
//                 (round-1 lesson: nontemporal no-allocate stores + 11532B
//                 row stride -> partial-sector HBM RMW, +120us regression).
//                 Each output row written entirely by its owning wave so L2
//                 merges the misaligned 256B segments into full lines.
// ---------------------------------------------------------------------------

#define TBL_TOTAL 376320            // 56*56*64 + 28*28*128 + 14*14*256 + 7*7*512
#define TBL_OFF0  0
#define TBL_OFF1  200704
#define TBL_OFF2  301056
#define TBL_OFF3  351232

__device__ __forceinline__ void compute_cams(const float* __restrict__ cams,
                                             double M[3][3], double o0[3],
                                             double cm[3][3][3], double om[3][3]) {
  // PI is np.float32(np.pi) in the reference; PI/180 stays f32-rounded.
  const double DEG  = (double)(3.14159274101257324f / 180.0f);
  const double PI_D = (double)3.14159274101257324f;
  for (int v = 0; v < 3; ++v) {
    double th = (double)cams[v * 5 + 0] * DEG;
    double ph = (double)cams[v * 5 + 1] * DEG;
    double dd = (double)cams[v * 5 + 3];
    double camy = dd * sin(ph);
    double lens = dd * cos(ph);
    double camx = lens * cos(th);
    double camz = lens * sin(th);
    double Zx = camx, Zy = camy, Zz = camz;
    double Yx = camy * cos(th + PI_D), Yy = lens, Yz = camy * sin(th + PI_D);
    double Xx = Yy * Zz - Yz * Zy;
    double Xy = Yz * Zx - Yx * Zz;
    double Xz = Yx * Zy - Yy * Zx;
    double nX = sqrt(Xx * Xx + Xy * Xy + Xz * Xz);
    double nY = sqrt(Yx * Yx + Yy * Yy + Yz * Yz);
    double nZ = sqrt(Zx * Zx + Zy * Zy + Zz * Zz);
    cm[v][0][0] = Xx / nX; cm[v][0][1] = Xy / nX; cm[v][0][2] = Xz / nX;
    cm[v][1][0] = Yx / nY; cm[v][1][1] = Yy / nY; cm[v][1][2] = Yz / nY;
    cm[v][2][0] = Zx / nZ; cm[v][2][1] = Zy / nZ; cm[v][2][2] = Zz / nZ;
    om[v][0] = Zx; om[v][1] = Zy; om[v][2] = Zz;
  }
  // A = c0^T ; M = inv(A) via adjugate (double precision).
  double a00 = cm[0][0][0], a01 = cm[0][1][0], a02 = cm[0][2][0];
  double a10 = cm[0][0][1], a11 = cm[0][1][1], a12 = cm[0][2][1];
  double a20 = cm[0][0][2], a21 = cm[0][1][2], a22 = cm[0][2][2];
  double det = a00 * (a11 * a22 - a12 * a21)
             - a01 * (a10 * a22 - a12 * a20)
             + a02 * (a10 * a21 - a11 * a20);
  M[0][0] = (a11 * a22 - a12 * a21) / det;
  M[0][1] = (a02 * a21 - a01 * a22) / det;
  M[0][2] = (a01 * a12 - a02 * a11) / det;
  M[1][0] = (a12 * a20 - a10 * a22) / det;
  M[1][1] = (a00 * a22 - a02 * a20) / det;
  M[1][2] = (a02 * a10 - a00 * a12) / det;
  M[2][0] = (a10 * a21 - a11 * a20) / det;
  M[2][1] = (a01 * a20 - a00 * a21) / det;
  M[2][2] = (a00 * a11 - a01 * a10) / det;
  o0[0] = om[0][0]; o0[1] = om[0][1]; o0[2] = om[0][2];
}

// Tiny setup kernel: camera params -> 48 doubles in workspace.
// Layout: M[9] | o0[3] | c[3][3][3] (27) | o[3][3] (9)
__global__ void k_setup(const float* __restrict__ cams, double* __restrict__ P) {
  if (threadIdx.x != 0 || blockIdx.x != 0) return;
  double M[3][3], o0[3], cm[3][3][3], om[3][3];
  compute_cams(cams, M, o0, cm, om);
  int i = 0;
  for (int r = 0; r < 3; ++r)
    for (int k = 0; k < 3; ++k) P[i++] = M[r][k];
  for (int k = 0; k < 3; ++k) P[i++] = o0[k];
  for (int v = 0; v < 3; ++v)
    for (int r = 0; r < 3; ++r)
      for (int k = 0; k < 3; ++k) P[i++] = cm[v][r][k];
  for (int v = 0; v < 3; ++v)
    for (int k = 0; k < 3; ++k) P[i++] = om[v][k];
}

// Transpose batch 0 of each feature level from [C,H,W] -> [H*W, C].
__global__ void k_transpose(const float* __restrict__ f0, const float* __restrict__ f1,
                            const float* __restrict__ f2, const float* __restrict__ f3,
                            float* __restrict__ tbl) {
  int i = blockIdx.x * 256 + threadIdx.x;
  if (i >= TBL_TOTAL) return;
  const float* src;
  int j, cmask, clog, HW;
  if (i < TBL_OFF1)      { src = f0; j = i;            cmask = 63;  clog = 6; HW = 3136; }
  else if (i < TBL_OFF2) { src = f1; j = i - TBL_OFF1; cmask = 127; clog = 7; HW = 784;  }
  else if (i < TBL_OFF3) { src = f2; j = i - TBL_OFF2; cmask = 255; clog = 8; HW = 196;  }
  else                   { src = f3; j = i - TBL_OFF3; cmask = 511; clog = 9; HW = 49;   }
  int c  = j & cmask;
  int hw = j >> clog;
  tbl[i] = src[c * HW + hw];   // batch 0 only (faithful truncated batch index)
}

// Per-point geometry: all double-precision work lives here (dense, all lanes
// active). Emits 12 absolute tbl offsets per point. No output writes here:
// each output row is written entirely by its k_gather wave (L2 line merging).
__global__ __launch_bounds__(256) void k_geom(const float* __restrict__ inpts,
                                              const double* __restrict__ P,
                                              int* __restrict__ off, int N) {
  int p = blockIdx.x * 256 + threadIdx.x;
  if (p >= N) return;
  double x = (double)inpts[p * 3 + 0];
  double y = (double)inpts[p * 3 + 1];
  double z = (double)inpts[p * 3 + 2];
  // point_origin = inputs @ inv(c0^T) + o0
  double p0 = x * P[0] + y * P[3] + z * P[6] + P[9];
  double p1 = x * P[1] + y * P[4] + z * P[7] + P[10];
  double p2 = x * P[2] + y * P[5] + z * P[8] + P[11];
  int4 r[3];
  #pragma unroll
  for (int v = 0; v < 3; ++v) {
    const double* cmv = P + 12 + v * 9;
    const double* ovv = P + 39 + v * 3;
    double q0 = p0 - ovv[0], q1 = p1 - ovv[1], q2 = p2 - ovv[2];
    double Xc = q0 * cmv[0] + q1 * cmv[1] + q2 * cmv[2];
    double Yc = q0 * cmv[3] + q1 * cmv[4] + q2 * cmv[5];
    double Zc = q0 * cmv[6] + q1 * cmv[7] + q2 * cmv[8];
    double nz = -Zc;
    double hv = 248.0 * (-Yc) / nz + 112.0;
    double wv = 248.0 * Xc / nz + 112.0;
    if (isnan(hv)) hv = 0.0;
    if (isnan(wv)) wv = 0.0;
    hv = fmin(fmax(hv, 0.0), 223.0);
    wv = fmin(fmax(wv, 0.0), 223.0);
    // scales 224/size = {4,8,16,32} are exact powers of two
    int h0 = (int)(hv * 0.25),    w0 = (int)(wv * 0.25);
    int h1 = (int)(hv * 0.125),   w1 = (int)(wv * 0.125);
    int h2 = (int)(hv * 0.0625),  w2 = (int)(wv * 0.0625);
    int h3 = (int)(hv * 0.03125), w3 = (int)(wv * 0.03125);
    r[v].x = TBL_OFF0 + (h0 * 56 + w0) * 64;
    r[v].y = TBL_OFF1 + (h1 * 28 + w1) * 128;
    r[v].z = TBL_OFF2 + (h2 * 14 + w2) * 256;
    r[v].w = TBL_OFF3 + (h3 * 7  + w3) * 512;
  }
  int4* op = (int4*)(off + p * 12);   // p*48 bytes, 16B-aligned
  op[0] = r[0]; op[1] = r[1]; op[2] = r[2];
}

// One wave per point: 15 fully-unrolled 64-channel slabs, level known at
// compile time per slab (no divergence, no LDS, no barrier, no doubles).
// Normal stores: misaligned 256B wave segments merge into full lines in L2.
__global__ __launch_bounds__(256) void k_gather(const int* __restrict__ off,
                                                const float* __restrict__ tbl,
                                                const float* __restrict__ inpts,
                                                float* __restrict__ out, int N) {
  const int wid = (blockIdx.x << 2) | (threadIdx.x >> 6);   // 4 waves/block
  if (wid >= N) return;
  const int lane = threadIdx.x & 63;
  const int4* ob = (const int4*)(off + wid * 12);
  const int4 o0 = ob[0];   // view 0: offsets for levels 0..3
  const int4 o1 = ob[1];   // view 1
  const int4 o2 = ob[2];   // view 2
  float* __restrict__ row = out + (size_t)wid * 2883;

  if (lane < 3) row[lane] = inpts[wid * 3 + lane];   // xyz passthrough

#define DO64(BASE_C, OO0, OO1, OO2, CL)                         \
  {                                                             \
    float v0 = tbl[(OO0) + (CL)];                               \
    float v1 = tbl[(OO1) + (CL)];                               \
    float v2 = tbl[(OO2) + (CL)];                               \
    float mx = fmaxf(fmaxf(v0, v1), v2);                        \
    float sm = (v0 + v1) + v2;                                  \
    float mean = sm / 3.0f;                                     \
    float d0 = v0 - mean, d1 = v1 - mean, d2 = v2 - mean;       \
    float var = ((d0 * d0 + d1 * d1) + d2 * d2) / 3.0f;         \
    float sd = sqrtf(var);                                      \
    int c = (BASE_C) + (CL);                                    \
    row[3 + c]    = mx;                                         \
    row[963 + c]  = mean;                                       \
    row[1923 + c] = sd;                                         \
  }

  // level 0: channels [0,64)
  DO64(0, o0.x, o1.x, o2.x, lane);
  // level 1: channels [64,192)
  #pragma unroll
  for (int j = 0; j < 2; ++j) DO64(64, o0.y, o1.y, o2.y, lane + 64 * j);
  // level 2: channels [192,448)
  #pragma unroll
  for (int j = 0; j < 4; ++j) DO64(192, o0.z, o1.z, o2.z, lane + 64 * j);
  // level 3: channels [448,960)
  #pragma unroll
  for (int j = 0; j < 8; ++j) DO64(448, o0.w, o1.w, o2.w, lane + 64 * j);
#undef DO64
}

// ---------------------------------------------------------------------------
// Fallback (ws too small): previous-session fused kernel, unchanged.
// ---------------------------------------------------------------------------
template <bool TRANSPOSED>
__global__ __launch_bounds__(256) void k_main(
    const float* __restrict__ inpts, const float* __restrict__ cams,
    const double* __restrict__ P, const float* __restrict__ tbl,
    const float* __restrict__ f0, const float* __restrict__ f1,
    const float* __restrict__ f2, const float* __restrict__ f3,
    float* __restrict__ out) {
  __shared__ int s_off[3][4];
  const int p = blockIdx.x;
  const int tid = threadIdx.x;

  if (tid < 3) {
    const int v = tid;
    double M[3][3], o0[3], cmv[3][3], ovv[3];
    if (TRANSPOSED) {
      M[0][0] = P[0]; M[0][1] = P[1]; M[0][2] = P[2];
      M[1][0] = P[3]; M[1][1] = P[4]; M[1][2] = P[5];
      M[2][0] = P[6]; M[2][1] = P[7]; M[2][2] = P[8];
      o0[0] = P[9]; o0[1] = P[10]; o0[2] = P[11];
      for (int r = 0; r < 3; ++r)
        for (int k = 0; k < 3; ++k) cmv[r][k] = P[12 + v * 9 + r * 3 + k];
      ovv[0] = P[39 + v * 3 + 0]; ovv[1] = P[39 + v * 3 + 1]; ovv[2] = P[39 + v * 3 + 2];
    } else {
      double cm[3][3][3], om[3][3];
      compute_cams(cams, M, o0, cm, om);
      for (int r = 0; r < 3; ++r)
        for (int k = 0; k < 3; ++k) cmv[r][k] = cm[v][r][k];
      ovv[0] = om[v][0]; ovv[1] = om[v][1]; ovv[2] = om[v][2];
    }
    double x = (double)inpts[p * 3 + 0];
    double y = (double)inpts[p * 3 + 1];
    double z = (double)inpts[p * 3 + 2];
    double p0 = x * M[0][0] + y * M[1][0] + z * M[2][0] + o0[0];
    double p1 = x * M[0][1] + y * M[1][1] + z * M[2][1] + o0[1];
    double p2 = x * M[0][2] + y * M[1][2] + z * M[2][2] + o0[2];
    double q0 = p0 - ovv[0], q1 = p1 - ovv[1], q2 = p2 - ovv[2];
    double Xc = q0 * cmv[0][0] + q1 * cmv[0][1] + q2 * cmv[0][2];
    double Yc = q0 * cmv[1][0] + q1 * cmv[1][1] + q2 * cmv[1][2];
    double Zc = q0 * cmv[2][0] + q1 * cmv[2][1] + q2 * cmv[2][2];
    double nz = -Zc;
    double hv = 248.0 * (-Yc) / nz + 112.0;
    double wv = 248.0 * Xc / nz + 112.0;
    if (isnan(hv)) hv = 0.0;
    if (isnan(wv)) wv = 0.0;
    hv = fmin(fmax(hv, 0.0), 223.0);
    wv = fmin(fmax(wv, 0.0), 223.0);
    int h0 = (int)(hv * 0.25),    w0 = (int)(wv * 0.25);
    int h1 = (int)(hv * 0.125),   w1 = (int)(wv * 0.125);
    int h2 = (int)(hv * 0.0625),  w2 = (int)(wv * 0.0625);
    int h3 = (int)(hv * 0.03125), w3 = (int)(wv * 0.03125);
    if (TRANSPOSED) {
      s_off[v][0] = TBL_OFF0 + (h0 * 56 + w0) * 64;
      s_off[v][1] = TBL_OFF1 + (h1 * 28 + w1) * 128;
      s_off[v][2] = TBL_OFF2 + (h2 * 14 + w2) * 256;
      s_off[v][3] = TBL_OFF3 + (h3 * 7  + w3) * 512;
    } else {
      s_off[v][0] = h0 * 56 + w0;
      s_off[v][1] = h1 * 28 + w1;
      s_off[v][2] = h2 * 14 + w2;
      s_off[v][3] = h3 * 7  + w3;
    }
    out[p * 2883 + v] = inpts[p * 3 + v];   // passthrough xyz
  }
  __syncthreads();

  const int row = p * 2883;
  for (int c = tid; c < 960; c += 256) {
    int l, cl;
    if (c < 64)       { l = 0; cl = c; }
    else if (c < 192) { l = 1; cl = c - 64; }
    else if (c < 448) { l = 2; cl = c - 192; }
    else              { l = 3; cl = c - 448; }
    float v0, v1, v2;
    if (TRANSPOSED) {
      v0 = tbl[s_off[0][l] + cl];
      v1 = tbl[s_off[1][l] + cl];
      v2 = tbl[s_off[2][l] + cl];
    } else {
      const float* f = (l == 0) ? f0 : (l == 1) ? f1 : (l == 2) ? f2 : f3;
      const int HW   = (l == 0) ? 3136 : (l == 1) ? 784 : (l == 2) ? 196 : 49;
      v0 = f[cl * HW + s_off[0][l]];
      v1 = f[cl * HW + s_off[1][l]];
      v2 = f[cl * HW + s_off[2][l]];
    }
    float mx = fmaxf(fmaxf(v0, v1), v2);
    float sm = (v0 + v1) + v2;
    float mean = sm / 3.0f;
    float d0 = v0 - mean, d1 = v1 - mean, d2 = v2 - mean;
    float var = ((d0 * d0 + d1 * d1) + d2 * d2) / 3.0f;
    float sd = sqrtf(var);
    out[row + 3 + c]    = mx;
    out[row + 963 + c]  = mean;
    out[row + 1923 + c] = sd;
  }
}

extern "C" void kernel_launch(void* const* d_in, const int* in_sizes, int n_in,
                              void* d_out, int out_size, void* d_ws, size_t ws_size,
                              hipStream_t stream) {
  const float* inpts = (const float*)d_in[0];
  const float* cams  = (const float*)d_in[1];
  const float* f0    = (const float*)d_in[2];
  const float* f1    = (const float*)d_in[3];
  const float* f2    = (const float*)d_in[4];
  const float* f3    = (const float*)d_in[5];
  float* out = (float*)d_out;
  const int N = in_sizes[0] / 3;

  const size_t TBL_BYTE_OFF = 512;
  const size_t OFF_BYTE_OFF = TBL_BYTE_OFF + (size_t)TBL_TOTAL * sizeof(float); // 1505792, 16B-aligned
  const size_t NEED_FULL = OFF_BYTE_OFF + (size_t)N * 12 * sizeof(int);
  const size_t NEED_MID  = TBL_BYTE_OFF + (size_t)TBL_TOTAL * sizeof(float);

  if (ws_size >= NEED_FULL) {
    double* P  = (double*)d_ws;
    float* tbl = (float*)((char*)d_ws + TBL_BYTE_OFF);
    int*   off = (int*)((char*)d_ws + OFF_BYTE_OFF);
    k_setup<<<1, 64, 0, stream>>>(cams, P);
    k_transpose<<<(TBL_TOTAL + 255) / 256, 256, 0, stream>>>(f0, f1, f2, f3, tbl);
    k_geom<<<(N + 255) / 256, 256, 0, stream>>>(inpts, P, off, N);
    k_gather<<<(N + 3) / 4, 256, 0, stream>>>(off, tbl, inpts, out, N);
  } else if (ws_size >= NEED_MID) {
    double* P  = (double*)d_ws;
    float* tbl = (float*)((char*)d_ws + TBL_BYTE_OFF);
    k_setup<<<1, 64, 0, stream>>>(cams, P);
    k_transpose<<<(TBL_TOTAL + 255) / 256, 256, 0, stream>>>(f0, f1, f2, f3, tbl);
    k_main<true><<<N, 256, 0, stream>>>(inpts, cams, P, tbl, f0, f1, f2, f3, out);
  } else {
    // Fallback: no workspace -> inline camera math, direct (uncoalesced) gather.
    k_main<false><<<N, 256, 0, stream>>>(inpts, cams, nullptr, nullptr, f0, f1, f2, f3, out);
  }
}

// Round 3
// 812.812 us; speedup vs baseline: 1.1639x; 1.0072x over previous
//
#include <hip/hip_runtime.h>
#include <math.h>

// ---------------------------------------------------------------------------
// GraphProjection: project N=65536 points into V=3 camera views, gather
// multi-scale CNN features (batch index faithfully truncates to 0), reduce
// max/mean/biased-std over views. Output [N, 3 + 3*960] f32.
//
// Cost model (validated R0-R2): timed graph = poison fill (~490us, 3.02GB,
// fixed) + harness reset memsets (~155us, fixed) + our kernels (~170us).
// k_gather is HBM-write-bound (756MB out, floor ~120us). R1 proved L2 write
// merging matters: nontemporal stores cost +128us (RMW on misaligned 256B
// segments). This revision trims instruction overhead + launch seams:
//   k_prep   : setup (1 thread) + transpose fused in one launch
//   k_geom   : per-point f64 projection -> 12 table offsets (dense, 1024 waves)
//   k_gather : one wave/point, float4 loads (aligned) + float4 stores
//              (memcpy, 4B-aligned ok on gfx950), s_load'd uniform offsets,
//              branchless per-lane level select. Arithmetic bit-identical
//              to the R2 passing kernel.
// ---------------------------------------------------------------------------

#define TBL_TOTAL 376320            // 56*56*64 + 28*28*128 + 14*14*256 + 7*7*512
#define TBL_OFF0  0
#define TBL_OFF1  200704
#define TBL_OFF2  301056
#define TBL_OFF3  351232

typedef float vf4 __attribute__((ext_vector_type(4)));

__device__ __forceinline__ void compute_cams(const float* __restrict__ cams,
                                             double M[3][3], double o0[3],
                                             double cm[3][3][3], double om[3][3]) {
  // PI is np.float32(np.pi) in the reference; PI/180 stays f32-rounded.
  const double DEG  = (double)(3.14159274101257324f / 180.0f);
  const double PI_D = (double)3.14159274101257324f;
  for (int v = 0; v < 3; ++v) {
    double th = (double)cams[v * 5 + 0] * DEG;
    double ph = (double)cams[v * 5 + 1] * DEG;
    double dd = (double)cams[v * 5 + 3];
    double camy = dd * sin(ph);
    double lens = dd * cos(ph);
    double camx = lens * cos(th);
    double camz = lens * sin(th);
    double Zx = camx, Zy = camy, Zz = camz;
    double Yx = camy * cos(th + PI_D), Yy = lens, Yz = camy * sin(th + PI_D);
    double Xx = Yy * Zz - Yz * Zy;
    double Xy = Yz * Zx - Yx * Zz;
    double Xz = Yx * Zy - Yy * Zx;
    double nX = sqrt(Xx * Xx + Xy * Xy + Xz * Xz);
    double nY = sqrt(Yx * Yx + Yy * Yy + Yz * Yz);
    double nZ = sqrt(Zx * Zx + Zy * Zy + Zz * Zz);
    cm[v][0][0] = Xx / nX; cm[v][0][1] = Xy / nX; cm[v][0][2] = Xz / nX;
    cm[v][1][0] = Yx / nY; cm[v][1][1] = Yy / nY; cm[v][1][2] = Yz / nY;
    cm[v][2][0] = Zx / nZ; cm[v][2][1] = Zy / nZ; cm[v][2][2] = Zz / nZ;
    om[v][0] = Zx; om[v][1] = Zy; om[v][2] = Zz;
  }
  // A = c0^T ; M = inv(A) via adjugate (double precision).
  double a00 = cm[0][0][0], a01 = cm[0][1][0], a02 = cm[0][2][0];
  double a10 = cm[0][0][1], a11 = cm[0][1][1], a12 = cm[0][2][1];
  double a20 = cm[0][0][2], a21 = cm[0][1][2], a22 = cm[0][2][2];
  double det = a00 * (a11 * a22 - a12 * a21)
             - a01 * (a10 * a22 - a12 * a20)
             + a02 * (a10 * a21 - a11 * a20);
  M[0][0] = (a11 * a22 - a12 * a21) / det;
  M[0][1] = (a02 * a21 - a01 * a22) / det;
  M[0][2] = (a01 * a12 - a02 * a11) / det;
  M[1][0] = (a12 * a20 - a10 * a22) / det;
  M[1][1] = (a00 * a22 - a02 * a20) / det;
  M[1][2] = (a02 * a10 - a00 * a12) / det;
  M[2][0] = (a10 * a21 - a11 * a20) / det;
  M[2][1] = (a01 * a20 - a00 * a21) / det;
  M[2][2] = (a00 * a11 - a01 * a10) / det;
  o0[0] = om[0][0]; o0[1] = om[0][1]; o0[2] = om[0][2];
}

// Fused: camera setup (global thread 0) + feature transpose (all threads).
// Transpose: batch 0 of each level [C,H,W] -> tbl [H*W, C].
__global__ void k_prep(const float* __restrict__ cams, double* __restrict__ P,
                       const float* __restrict__ f0, const float* __restrict__ f1,
                       const float* __restrict__ f2, const float* __restrict__ f3,
                       float* __restrict__ tbl) {
  int i = blockIdx.x * 256 + threadIdx.x;
  if (i == 0) {
    double M[3][3], o0[3], cm[3][3][3], om[3][3];
    compute_cams(cams, M, o0, cm, om);
    int k = 0;
    for (int r = 0; r < 3; ++r)
      for (int c = 0; c < 3; ++c) P[k++] = M[r][c];
    for (int c = 0; c < 3; ++c) P[k++] = o0[c];
    for (int v = 0; v < 3; ++v)
      for (int r = 0; r < 3; ++r)
        for (int c = 0; c < 3; ++c) P[k++] = cm[v][r][c];
    for (int v = 0; v < 3; ++v)
      for (int c = 0; c < 3; ++c) P[k++] = om[v][c];
  }
  if (i >= TBL_TOTAL) return;
  const float* src;
  int j, cmask, clog, HW;
  if (i < TBL_OFF1)      { src = f0; j = i;            cmask = 63;  clog = 6; HW = 3136; }
  else if (i < TBL_OFF2) { src = f1; j = i - TBL_OFF1; cmask = 127; clog = 7; HW = 784;  }
  else if (i < TBL_OFF3) { src = f2; j = i - TBL_OFF2; cmask = 255; clog = 8; HW = 196;  }
  else                   { src = f3; j = i - TBL_OFF3; cmask = 511; clog = 9; HW = 49;   }
  int c  = j & cmask;
  int hw = j >> clog;
  tbl[i] = src[c * HW + hw];   // batch 0 only (faithful truncated batch index)
}

// Per-point geometry: all double-precision work lives here (dense, all lanes
// active). Emits 12 absolute tbl offsets per point. No output writes here.
__global__ __launch_bounds__(256) void k_geom(const float* __restrict__ inpts,
                                              const double* __restrict__ P,
                                              int* __restrict__ off, int N) {
  int p = blockIdx.x * 256 + threadIdx.x;
  if (p >= N) return;
  double x = (double)inpts[p * 3 + 0];
  double y = (double)inpts[p * 3 + 1];
  double z = (double)inpts[p * 3 + 2];
  // point_origin = inputs @ inv(c0^T) + o0
  double p0 = x * P[0] + y * P[3] + z * P[6] + P[9];
  double p1 = x * P[1] + y * P[4] + z * P[7] + P[10];
  double p2 = x * P[2] + y * P[5] + z * P[8] + P[11];
  int4 r[3];
  #pragma unroll
  for (int v = 0; v < 3; ++v) {
    const double* cmv = P + 12 + v * 9;
    const double* ovv = P + 39 + v * 3;
    double q0 = p0 - ovv[0], q1 = p1 - ovv[1], q2 = p2 - ovv[2];
    double Xc = q0 * cmv[0] + q1 * cmv[1] + q2 * cmv[2];
    double Yc = q0 * cmv[3] + q1 * cmv[4] + q2 * cmv[5];
    double Zc = q0 * cmv[6] + q1 * cmv[7] + q2 * cmv[8];
    double nz = -Zc;
    double hv = 248.0 * (-Yc) / nz + 112.0;
    double wv = 248.0 * Xc / nz + 112.0;
    if (isnan(hv)) hv = 0.0;
    if (isnan(wv)) wv = 0.0;
    hv = fmin(fmax(hv, 0.0), 223.0);
    wv = fmin(fmax(wv, 0.0), 223.0);
    // scales 224/size = {4,8,16,32} are exact powers of two
    int h0 = (int)(hv * 0.25),    w0 = (int)(wv * 0.25);
    int h1 = (int)(hv * 0.125),   w1 = (int)(wv * 0.125);
    int h2 = (int)(hv * 0.0625),  w2 = (int)(wv * 0.0625);
    int h3 = (int)(hv * 0.03125), w3 = (int)(wv * 0.03125);
    r[v].x = TBL_OFF0 + (h0 * 56 + w0) * 64;
    r[v].y = TBL_OFF1 + (h1 * 28 + w1) * 128;
    r[v].z = TBL_OFF2 + (h2 * 14 + w2) * 256;
    r[v].w = TBL_OFF3 + (h3 * 7  + w3) * 512;
  }
  int4* op = (int4*)(off + p * 12);   // p*48 bytes, 16B-aligned
  op[0] = r[0]; op[1] = r[1]; op[2] = r[2];
}

// Absolute table offset for channel c (branchless select chain).
__device__ __forceinline__ int levoff(const int4 o, int c) {
  int r = o.x + c;
  r = (c >= 64)  ? (o.y + (c - 64))  : r;
  r = (c >= 192) ? (o.z + (c - 192)) : r;
  r = (c >= 448) ? (o.w + (c - 448)) : r;
  return r;
}

// One wave per point, 4 chunks of 256 channels (last: 192). float4 table
// loads (16B-aligned by construction: level bases are multiples of 64 floats,
// c multiple of 4). float4 stores via memcpy (dst is 4B-aligned; gfx950
// handles unaligned global dwordx4, worst case the backend splits them).
// Normal (L2-allocating) stores: R1 proved nontemporal costs +128us RMW.
__global__ __launch_bounds__(256) void k_gather(const int* __restrict__ off,
                                                const float* __restrict__ tbl,
                                                const float* __restrict__ inpts,
                                                float* __restrict__ out, int N) {
  int wid = (blockIdx.x << 2) | ((int)threadIdx.x >> 6);   // 4 waves/block
  wid = __builtin_amdgcn_readfirstlane(wid);               // wave-uniform -> s_load
  if (wid >= N) return;
  const int lane = threadIdx.x & 63;
  const int4* ob = (const int4*)(off + wid * 12);
  const int4 o0 = ob[0];   // view 0: offsets for levels 0..3
  const int4 o1 = ob[1];   // view 1
  const int4 o2 = ob[2];   // view 2
  float* __restrict__ row = out + (size_t)wid * 2883;

  if (lane < 3) row[lane] = inpts[wid * 3 + lane];   // xyz passthrough

  const int c4 = lane << 2;
  #pragma unroll
  for (int it = 0; it < 4; ++it) {
    const int c = it * 256 + c4;
    if (c < 960) {
      const int t0 = levoff(o0, c);
      const int t1 = levoff(o1, c);
      const int t2 = levoff(o2, c);
      const vf4 a = *(const vf4*)(tbl + t0);
      const vf4 b = *(const vf4*)(tbl + t1);
      const vf4 e = *(const vf4*)(tbl + t2);
      vf4 mx, mn, sd;
      #pragma unroll
      for (int j = 0; j < 4; ++j) {
        float v0 = a[j], v1 = b[j], v2 = e[j];
        float m  = fmaxf(fmaxf(v0, v1), v2);
        float sm = (v0 + v1) + v2;
        float mean = sm / 3.0f;
        float d0 = v0 - mean, d1 = v1 - mean, d2 = v2 - mean;
        float var = ((d0 * d0 + d1 * d1) + d2 * d2) / 3.0f;
        mx[j] = m;
        mn[j] = mean;
        sd[j] = sqrtf(var);
      }
      __builtin_memcpy(row + 3 + c,    &mx, 16);
      __builtin_memcpy(row + 963 + c,  &mn, 16);
      __builtin_memcpy(row + 1923 + c, &sd, 16);
    }
  }
}

// ---------------------------------------------------------------------------
// Fallback (ws too small): previous-session fused kernel, unchanged.
// ---------------------------------------------------------------------------
template <bool TRANSPOSED>
__global__ __launch_bounds__(256) void k_main(
    const float* __restrict__ inpts, const float* __restrict__ cams,
    const double* __restrict__ P, const float* __restrict__ tbl,
    const float* __restrict__ f0, const float* __restrict__ f1,
    const float* __restrict__ f2, const float* __restrict__ f3,
    float* __restrict__ out) {
  __shared__ int s_off[3][4];
  const int p = blockIdx.x;
  const int tid = threadIdx.x;

  if (tid < 3) {
    const int v = tid;
    double M[3][3], o0[3], cmv[3][3], ovv[3];
    if (TRANSPOSED) {
      M[0][0] = P[0]; M[0][1] = P[1]; M[0][2] = P[2];
      M[1][0] = P[3]; M[1][1] = P[4]; M[1][2] = P[5];
      M[2][0] = P[6]; M[2][1] = P[7]; M[2][2] = P[8];
      o0[0] = P[9]; o0[1] = P[10]; o0[2] = P[11];
      for (int r = 0; r < 3; ++r)
        for (int k = 0; k < 3; ++k) cmv[r][k] = P[12 + v * 9 + r * 3 + k];
      ovv[0] = P[39 + v * 3 + 0]; ovv[1] = P[39 + v * 3 + 1]; ovv[2] = P[39 + v * 3 + 2];
    } else {
      double cm[3][3][3], om[3][3];
      compute_cams(cams, M, o0, cm, om);
      for (int r = 0; r < 3; ++r)
        for (int k = 0; k < 3; ++k) cmv[r][k] = cm[v][r][k];
      ovv[0] = om[v][0]; ovv[1] = om[v][1]; ovv[2] = om[v][2];
    }
    double x = (double)inpts[p * 3 + 0];
    double y = (double)inpts[p * 3 + 1];
    double z = (double)inpts[p * 3 + 2];
    double p0 = x * M[0][0] + y * M[1][0] + z * M[2][0] + o0[0];
    double p1 = x * M[0][1] + y * M[1][1] + z * M[2][1] + o0[1];
    double p2 = x * M[0][2] + y * M[1][2] + z * M[2][2] + o0[2];
    double q0 = p0 - ovv[0], q1 = p1 - ovv[1], q2 = p2 - ovv[2];
    double Xc = q0 * cmv[0][0] + q1 * cmv[0][1] + q2 * cmv[0][2];
    double Yc = q0 * cmv[1][0] + q1 * cmv[1][1] + q2 * cmv[1][2];
    double Zc = q0 * cmv[2][0] + q1 * cmv[2][1] + q2 * cmv[2][2];
    double nz = -Zc;
    double hv = 248.0 * (-Yc) / nz + 112.0;
    double wv = 248.0 * Xc / nz + 112.0;
    if (isnan(hv)) hv = 0.0;
    if (isnan(wv)) wv = 0.0;
    hv = fmin(fmax(hv, 0.0), 223.0);
    wv = fmin(fmax(wv, 0.0), 223.0);
    int h0 = (int)(hv * 0.25),    w0 = (int)(wv * 0.25);
    int h1 = (int)(hv * 0.125),   w1 = (int)(wv * 0.125);
    int h2 = (int)(hv * 0.0625),  w2 = (int)(wv * 0.0625);
    int h3 = (int)(hv * 0.03125), w3 = (int)(wv * 0.03125);
    if (TRANSPOSED) {
      s_off[v][0] = TBL_OFF0 + (h0 * 56 + w0) * 64;
      s_off[v][1] = TBL_OFF1 + (h1 * 28 + w1) * 128;
      s_off[v][2] = TBL_OFF2 + (h2 * 14 + w2) * 256;
      s_off[v][3] = TBL_OFF3 + (h3 * 7  + w3) * 512;
    } else {
      s_off[v][0] = h0 * 56 + w0;
      s_off[v][1] = h1 * 28 + w1;
      s_off[v][2] = h2 * 14 + w2;
      s_off[v][3] = h3 * 7  + w3;
    }
    out[p * 2883 + v] = inpts[p * 3 + v];   // passthrough xyz
  }
  __syncthreads();

  const int row = p * 2883;
  for (int c = tid; c < 960; c += 256) {
    int l, cl;
    if (c < 64)       { l = 0; cl = c; }
    else if (c < 192) { l = 1; cl = c - 64; }
    else if (c < 448) { l = 2; cl = c - 192; }
    else              { l = 3; cl = c - 448; }
    float v0, v1, v2;
    if (TRANSPOSED) {
      v0 = tbl[s_off[0][l] + cl];
      v1 = tbl[s_off[1][l] + cl];
      v2 = tbl[s_off[2][l] + cl];
    } else {
      const float* f = (l == 0) ? f0 : (l == 1) ? f1 : (l == 2) ? f2 : f3;
      const int HW   = (l == 0) ? 3136 : (l == 1) ? 784 : (l == 2) ? 196 : 49;
      v0 = f[cl * HW + s_off[0][l]];
      v1 = f[cl * HW + s_off[1][l]];
      v2 = f[cl * HW + s_off[2][l]];
    }
    float mx = fmaxf(fmaxf(v0, v1), v2);
    float sm = (v0 + v1) + v2;
    float mean = sm / 3.0f;
    float d0 = v0 - mean, d1 = v1 - mean, d2 = v2 - mean;
    float var = ((d0 * d0 + d1 * d1) + d2 * d2) / 3.0f;
    float sd = sqrtf(var);
    out[row + 3 + c]    = mx;
    out[row + 963 + c]  = mean;
    out[row + 1923 + c] = sd;
  }
}

extern "C" void kernel_launch(void* const* d_in, const int* in_sizes, int n_in,
                              void* d_out, int out_size, void* d_ws, size_t ws_size,
                              hipStream_t stream) {
  const float* inpts = (const float*)d_in[0];
  const float* cams  = (const float*)d_in[1];
  const float* f0    = (const float*)d_in[2];
  const float* f1    = (const float*)d_in[3];
  const float* f2    = (const float*)d_in[4];
  const float* f3    = (const float*)d_in[5];
  float* out = (float*)d_out;
  const int N = in_sizes[0] / 3;

  const size_t TBL_BYTE_OFF = 512;
  const size_t OFF_BYTE_OFF = TBL_BYTE_OFF + (size_t)TBL_TOTAL * sizeof(float); // 1505792, 16B-aligned
  const size_t NEED_FULL = OFF_BYTE_OFF + (size_t)N * 12 * sizeof(int);
  const size_t NEED_MID  = TBL_BYTE_OFF + (size_t)TBL_TOTAL * sizeof(float);

  if (ws_size >= NEED_FULL) {
    double* P  = (double*)d_ws;
    float* tbl = (float*)((char*)d_ws + TBL_BYTE_OFF);
    int*   off = (int*)((char*)d_ws + OFF_BYTE_OFF);
    k_prep<<<(TBL_TOTAL + 255) / 256, 256, 0, stream>>>(cams, P, f0, f1, f2, f3, tbl);
    k_geom<<<(N + 255) / 256, 256, 0, stream>>>(inpts, P, off, N);
    k_gather<<<(N + 3) / 4, 256, 0, stream>>>(off, tbl, inpts, out, N);
  } else if (ws_size >= NEED_MID) {
    double* P  = (double*)d_ws;
    float* tbl = (float*)((char*)d_ws + TBL_BYTE_OFF);
    k_prep<<<(TBL_TOTAL + 255) / 256, 256, 0, stream>>>(cams, P, f0, f1, f2, f3, tbl);
    k_main<true><<<N, 256, 0, stream>>>(inpts, cams, P, tbl, f0, f1, f2, f3, out);
  } else {
    // Fallback: no workspace -> inline camera math, direct (uncoalesced) gather.
    k_main<false><<<N, 256, 0, stream>>>(inpts, cams, nullptr, nullptr, f0, f1, f2, f3, out);
  }
}